// Round 5
// baseline (636.923 us; speedup 1.0000x reference)
//
#include <hip/hip_runtime.h>
#include <cmath>

#define B_   64
#define LX_  1024
#define LY_  1024
#define D_   300
#define DP   320      // padded K / e dimension
#define DV   304      // padded d for PV (19 * 16)
#define BM   64       // s-tile rows per block (flash attn)
#define KV   32       // t-tile
#define NT   (LY_ / KV)

using f32x4  = __attribute__((ext_vector_type(4))) float;
using bf16x8 = __attribute__((ext_vector_type(8))) __bf16;
using u32x4  = __attribute__((ext_vector_type(4))) unsigned int;
using u32x2  = __attribute__((ext_vector_type(2))) unsigned int;

static __device__ __forceinline__ unsigned short f2b(float f){
    unsigned u = __builtin_bit_cast(unsigned, f);
    u += 0x7FFFu + ((u >> 16) & 1u);          // round-to-nearest-even
    return (unsigned short)(u >> 16);
}

static __device__ __forceinline__ unsigned pk_bf16(float lo, float hi){
    unsigned r;
    asm volatile("v_cvt_pk_bf16_f32 %0, %1, %2" : "=v"(r) : "v"(lo), "v"(hi));
    return r;
}

static __device__ __forceinline__ bf16x8 ld_bf8(const unsigned short* p){
    u32x4 u = *(const u32x4*)p;
    return __builtin_bit_cast(bf16x8, u);
}

static __device__ __forceinline__ f32x4 mfma16(bf16x8 a, bf16x8 b, f32x4 c){
    return __builtin_amdgcn_mfma_f32_16x16x32_bf16(a, b, c, 0, 0, 0);
}

// ---------------- K0: W (300x300 f32) -> Wb (320x320 bf16, zero padded) ----
__global__ void k_wconv(const float* __restrict__ W, unsigned short* __restrict__ Wb){
    int i = blockIdx.x * 256 + threadIdx.x;
    if (i >= DP * DP) return;
    int e = i / DP, d = i % DP;
    float v = (e < D_ && d < D_) ? W[e * D_ + d] : 0.f;
    Wb[i] = f2b(v);
}

// ---------------- K2: y (b,t,d f32) -> yT (b,d,t bf16), d padded to 304 ----
__global__ __launch_bounds__(256) void k_ytrans(const float* __restrict__ Y,
                                                unsigned short* __restrict__ yT){
    __shared__ float tile[64][65];
    const int bid = blockIdx.x;           // 64 * 16 * 5
    const int b  = bid / 80;
    const int tt = (bid % 80) / 5;
    const int dt = bid % 5;
    const int t0 = tt * 64, d0 = dt * 64;
    const int tid = threadIdx.x;
    const int dl = tid & 63, qq = tid >> 6;
    #pragma unroll
    for (int r = 0; r < 16; ++r){
        const int tl = qq * 16 + r;
        const int d = d0 + dl;
        float v = (d < D_) ? Y[((long)b * LY_ + t0 + tl) * D_ + d] : 0.f;
        tile[tl][dl] = v;
    }
    __syncthreads();
    #pragma unroll
    for (int r = 0; r < 16; ++r){
        const int drow = d0 + qq * 16 + r;
        if (drow < DV){
            float v = (drow < D_) ? tile[dl][qq * 16 + r] : 0.f;
            yT[((long)b * DV + drow) * LY_ + t0 + dl] = f2b(v);
        }
    }
}

// ---------------- K1: proj = relu(Z @ W^T + b), swapped-operand epilogue ----
// D.row = e (4 consecutive per lane), D.col = m-row -> packed b64 stores
__global__ __launch_bounds__(256) void k_proj(const float* __restrict__ X,
        const float* __restrict__ Y, const float* __restrict__ bias,
        const unsigned short* __restrict__ Wb,
        unsigned short* __restrict__ Px, unsigned short* __restrict__ Py){
    const int tid = threadIdx.x;
    const int w = tid >> 6, l = tid & 63;
    const int lr = l & 15, lg = l >> 4;
    const long m0 = (long)blockIdx.x * 128;
    const bool isX = (m0 < (long)B_ * LX_);
    const float* S = isX ? X : Y;
    unsigned short* Dst = isX ? Px : Py;
    const long base = isX ? m0 : m0 - (long)B_ * LX_;

    u32x4 a[2][10];
    #pragma unroll
    for (int ms = 0; ms < 2; ++ms){
        const float* rp = S + (base + 32 * w + 16 * ms + lr) * D_;
        #pragma unroll
        for (int ks = 0; ks < 10; ++ks){
            const int k0 = ks * 32 + lg * 8;
            f32x4 v0 = {0,0,0,0}, v1 = {0,0,0,0};
            if (k0 + 4 <= D_) v0 = *(const f32x4*)(rp + k0);
            if (k0 + 8 <= D_) v1 = *(const f32x4*)(rp + k0 + 4);
            u32x4 u;
            u[0] = pk_bf16(v0[0], v0[1]);
            u[1] = pk_bf16(v0[2], v0[3]);
            u[2] = pk_bf16(v1[0], v1[1]);
            u[3] = pk_bf16(v1[2], v1[3]);
            a[ms][ks] = u;
        }
    }

    #pragma unroll 2
    for (int es = 0; es < 20; ++es){
        f32x4 acc0 = {0,0,0,0}, acc1 = {0,0,0,0};
        const unsigned short* wp = Wb + (es * 16 + lr) * DP + lg * 8;
        #pragma unroll
        for (int ks = 0; ks < 10; ++ks){
            bf16x8 bf = ld_bf8(wp + ks * 32);       // A: row=e, k=d
            acc0 = mfma16(bf, __builtin_bit_cast(bf16x8, a[0][ks]), acc0);
            acc1 = mfma16(bf, __builtin_bit_cast(bf16x8, a[1][ks]), acc1);
        }
        // lane holds D[e = es*16 + 4*lg + r][m = lr]
        const int e0 = es * 16 + lg * 4;
        f32x4 bv = {0,0,0,0};
        if (e0 + 4 <= D_) bv = *(const f32x4*)(bias + e0);
        else {
            #pragma unroll
            for (int r = 0; r < 4; ++r) bv[r] = (e0 + r < D_) ? bias[e0 + r] : 0.f;
        }
        float s0[4], s1[4];
        #pragma unroll
        for (int r = 0; r < 4; ++r){
            float t0v = acc0[r] + bv[r]; s0[r] = t0v > 0.f ? t0v : 0.f;
            float t1v = acc1[r] + bv[r]; s1[r] = t1v > 0.f ? t1v : 0.f;
        }
        const u32x2 o0 = { pk_bf16(s0[0], s0[1]), pk_bf16(s0[2], s0[3]) };
        const u32x2 o1 = { pk_bf16(s1[0], s1[1]), pk_bf16(s1[2], s1[3]) };
        *(u32x2*)(Dst + (base + 32 * w + lr) * DP + e0)      = o0;
        *(u32x2*)(Dst + (base + 32 * w + 16 + lr) * DP + e0) = o1;
    }
}

// ---------------- K3: flash attention ---------------------------------------
// Yp staged in LDS (prefetch-split); yT PV fragments DIRECT from global
// (4-wave redundancy absorbed by L1/L2 instead of the saturated LDS pipe)
__global__ __launch_bounds__(256, 3) void k_attn(const int* __restrict__ mask,
        const unsigned short* __restrict__ Px, const unsigned short* __restrict__ Py,
        const unsigned short* __restrict__ yT, float* __restrict__ out){
    __shared__ unsigned short Yp_lds[KV][328];
    __shared__ unsigned short P_lds[BM][40];     // [s within block][t]

    const int tid = threadIdx.x;
    const int w = tid >> 6, l = tid & 63;
    const int lr = l & 15, lg = l >> 4;

    // XCD-bijective swizzle: all 16 s-blocks of a batch land on one XCD
    const int bid = blockIdx.x;              // 1024
    const int xcd = bid & 7;
    const int g = bid >> 3;
    const int b = xcd + 8 * (g >> 4);
    const int s0 = (g & 15) * BM;

    // Q fragments: wave w owns rows s0+16w .. s0+16w+15 (B-operand: col = lr)
    u32x4 q[10];
    {
        const unsigned short* qp = Px + ((long)b * LX_ + s0 + 16 * w + lr) * DP + lg * 8;
        #pragma unroll
        for (int ks = 0; ks < 10; ++ks) q[ks] = *(const u32x4*)(qp + ks * 32);
    }

    // staging addresses for Yp (coalesced: tile is contiguous 20KB in Py? rows
    // are DP-strided; per thread 5 chunks)
    const unsigned short* srcYp[5];
    unsigned short*       dstYp[5];
    #pragma unroll
    for (int j = 0; j < 5; ++j){
        const int id = tid + 256 * j;            // 0..1279
        const int row = id / 40, c = id % 40;
        srcYp[j] = Py + ((long)b * LY_ + row) * DP + c * 8;
        dstYp[j] = &Yp_lds[row][c * 8];
    }

    // PV fragment base: lane reads yT[b, n*16+lr, t0 + lg*8 .. +7]
    const unsigned short* vbase = yT + ((long)b * DV + lr) * LY_ + lg * 8;

    const int* mrow = mask + (long)b * LY_;

    // ---- prologue: stage tile 0 ----
    u32x4 pA[5];
    #pragma unroll
    for (int j = 0; j < 5; ++j) pA[j] = *(const u32x4*)srcYp[j];
    int4 m0v = *(const int4*)(mrow + lg * 4);
    int4 m1v = *(const int4*)(mrow + 16 + lg * 4);
    #pragma unroll
    for (int j = 0; j < 5; ++j) *(u32x4*)dstYp[j] = pA[j];
    __syncthreads();

    f32x4 acc[19];
    #pragma unroll
    for (int n = 0; n < 19; ++n) acc[n] = f32x4{0,0,0,0};
    float m_r = -INFINITY;    // running max for s-row = s0+16w+lr
    float l_r = 0.f;

    for (int it = 0; it < NT; ++it){
        const bool notlast = (it < NT - 1);

        // ---- A: issue next tile's global loads (consumed after barrier) ----
        int4 mn0, mn1;
        if (notlast){
            #pragma unroll
            for (int j = 0; j < 5; ++j){ srcYp[j] += KV * DP; pA[j] = *(const u32x4*)srcYp[j]; }
            mn0 = *(const int4*)(mrow + (it + 1) * KV + lg * 4);
            mn1 = *(const int4*)(mrow + (it + 1) * KV + 16 + lg * 4);
        }

        // ---- B: compute on current tile (skip if fully masked) ----
        const int allm = (m0v.x && m0v.y && m0v.z && m0v.w &&
                          m1v.x && m1v.y && m1v.z && m1v.w) ? 1 : 0;
        if (!__all(allm)){
            // S^T = Yp @ Q^T : lane holds S[t = it*KV + 16*sub + 4*lg + r][s = s0+16w+lr]
            f32x4 sv0 = {0,0,0,0}, sv1 = {0,0,0,0};
            #pragma unroll
            for (int ks = 0; ks < 10; ++ks){
                bf16x8 qf = __builtin_bit_cast(bf16x8, q[ks]);
                bf16x8 a0 = ld_bf8(&Yp_lds[lr][ks * 32 + lg * 8]);
                bf16x8 a1 = ld_bf8(&Yp_lds[16 + lr][ks * 32 + lg * 8]);
                sv0 = mfma16(a0, qf, sv0);
                sv1 = mfma16(a1, qf, sv1);
            }

            float v0[4], v1[4];
            v0[0] = sv0[0] + (m0v.x ? -3.0e38f : 0.f);
            v0[1] = sv0[1] + (m0v.y ? -3.0e38f : 0.f);
            v0[2] = sv0[2] + (m0v.z ? -3.0e38f : 0.f);
            v0[3] = sv0[3] + (m0v.w ? -3.0e38f : 0.f);
            v1[0] = sv1[0] + (m1v.x ? -3.0e38f : 0.f);
            v1[1] = sv1[1] + (m1v.y ? -3.0e38f : 0.f);
            v1[2] = sv1[2] + (m1v.z ? -3.0e38f : 0.f);
            v1[3] = sv1[3] + (m1v.w ? -3.0e38f : 0.f);

            float mx = fmaxf(fmaxf(fmaxf(v0[0], v0[1]), fmaxf(v0[2], v0[3])),
                             fmaxf(fmaxf(v1[0], v1[1]), fmaxf(v1[2], v1[3])));
            mx = fmaxf(mx, __shfl_xor(mx, 16));
            mx = fmaxf(mx, __shfl_xor(mx, 32));
            const float nm = fmaxf(m_r, mx);

            float p0[4], p1[4];
            float ps = 0.f;
            #pragma unroll
            for (int r = 0; r < 4; ++r){
                p0[r] = __expf(v0[r] - nm);
                p1[r] = __expf(v1[r] - nm);
                ps += p0[r] + p1[r];
            }
            ps += __shfl_xor(ps, 16);
            ps += __shfl_xor(ps, 32);
            const float sc = __expf(m_r - nm);   // first tile: exp(-inf)=0
            l_r = l_r * sc + ps;
            m_r = nm;

            // rescale acc rows (s = 4*lg + r): broadcast sc from lane 4*lg+r
            float scr[4];
            #pragma unroll
            for (int r = 0; r < 4; ++r) scr[r] = __shfl(sc, lg * 4 + r);
            #pragma unroll
            for (int n = 0; n < 19; ++n){
                #pragma unroll
                for (int r = 0; r < 4; ++r) acc[n][r] *= scr[r];
            }

            // pack P -> bf16, write own wave's rows (within-wave dependency only)
            const unsigned c00 = pk_bf16(p0[0], p0[1]);
            const unsigned c01 = pk_bf16(p0[2], p0[3]);
            const unsigned c10 = pk_bf16(p1[0], p1[1]);
            const unsigned c11 = pk_bf16(p1[2], p1[3]);
            *(u32x2*)&P_lds[16 * w + lr][4 * lg]      = u32x2{c00, c01};
            *(u32x2*)&P_lds[16 * w + lr][16 + 4 * lg] = u32x2{c10, c11};

            // O += P @ y : B-fragments straight from global (L1/L2-serviced)
            bf16x8 pf = ld_bf8(&P_lds[16 * w + lr][lg * 8]);
            const unsigned short* vp = vbase + it * KV;
            #pragma unroll
            for (int n = 0; n < 19; ++n){
                bf16x8 vf = ld_bf8(vp + n * 16 * LY_);
                acc[n] = mfma16(pf, vf, acc[n]);
            }
        }

        __syncthreads();           // all waves done reading Yp_lds
        if (notlast){
            #pragma unroll
            for (int j = 0; j < 5; ++j) *(u32x4*)dstYp[j] = pA[j];
            m0v = mn0; m1v = mn1;
        }
        __syncthreads();           // LDS ready for next iteration
    }

    // normalize: 1/l for rows s = 4*lg + r via broadcast
    const float il = 1.f / l_r;
    float invr[4];
    #pragma unroll
    for (int r = 0; r < 4; ++r) invr[r] = __shfl(il, lg * 4 + r);

    #pragma unroll
    for (int n = 0; n < 19; ++n){
        const int d = n * 16 + lr;
        if (d < D_){
            #pragma unroll
            for (int r = 0; r < 4; ++r){
                out[((long)b * LX_ + s0 + 16 * w + lg * 4 + r) * D_ + d] = acc[n][r] * invr[r];
            }
        }
    }
}

extern "C" void kernel_launch(void* const* d_in, const int* in_sizes, int n_in,
                              void* d_out, int out_size, void* d_ws, size_t ws_size,
                              hipStream_t stream){
    const float* x = (const float*)d_in[0];
    const float* y = (const float*)d_in[1];
    const int* ymask = (const int*)d_in[2];
    const float* W = (const float*)d_in[3];
    const float* bias = (const float*)d_in[4];
    float* out = (float*)d_out;

    unsigned short* Wb  = (unsigned short*)d_ws;
    unsigned short* Px  = (unsigned short*)((char*)d_ws + (1 << 18));
    unsigned short* Py  = (unsigned short*)((char*)d_ws + (1 << 18) + 41943040LL);
    unsigned short* yTw = (unsigned short*)((char*)d_ws + (1 << 18) + 83886080LL);

    hipLaunchKernelGGL(k_wconv, dim3((DP * DP + 255) / 256), dim3(256), 0, stream, W, Wb);
    hipLaunchKernelGGL(k_proj,  dim3(1024), dim3(256), 0, stream, x, y, bias, Wb, Px, Py);
    hipLaunchKernelGGL(k_ytrans, dim3(64 * 80), dim3(256), 0, stream, y, yTw);
    hipLaunchKernelGGL(k_attn,  dim3(1024), dim3(256), 0, stream, ymask, Px, Py, yTw, out);
}

// Round 6
// 597.434 us; speedup vs baseline: 1.0661x; 1.0661x over previous
//
#include <hip/hip_runtime.h>
#include <cmath>

#define B_   64
#define LX_  1024
#define LY_  1024
#define D_   300
#define DP   320      // padded K / e dimension
#define DV   304      // padded d for PV (19 * 16)
#define BM   128      // s-tile rows per block (2 groups of 64)
#define KV   32       // t-tile
#define NT   (LY_ / KV)

using f32x4  = __attribute__((ext_vector_type(4))) float;
using bf16x8 = __attribute__((ext_vector_type(8))) __bf16;
using u32x4  = __attribute__((ext_vector_type(4))) unsigned int;
using u32x2  = __attribute__((ext_vector_type(2))) unsigned int;

static __device__ __forceinline__ unsigned short f2b(float f){
    unsigned u = __builtin_bit_cast(unsigned, f);
    u += 0x7FFFu + ((u >> 16) & 1u);          // round-to-nearest-even
    return (unsigned short)(u >> 16);
}

static __device__ __forceinline__ unsigned pk_bf16(float lo, float hi){
    unsigned r;
    asm volatile("v_cvt_pk_bf16_f32 %0, %1, %2" : "=v"(r) : "v"(lo), "v"(hi));
    return r;
}

static __device__ __forceinline__ bf16x8 ld_bf8(const unsigned short* p){
    u32x4 u = *(const u32x4*)p;
    return __builtin_bit_cast(bf16x8, u);
}

static __device__ __forceinline__ f32x4 mfma16(bf16x8 a, bf16x8 b, f32x4 c){
    return __builtin_amdgcn_mfma_f32_16x16x32_bf16(a, b, c, 0, 0, 0);
}

// ---------------- K0: W (300x300 f32) -> Wb (320x320 bf16, zero padded) ----
__global__ void k_wconv(const float* __restrict__ W, unsigned short* __restrict__ Wb){
    int i = blockIdx.x * 256 + threadIdx.x;
    if (i >= DP * DP) return;
    int e = i / DP, d = i % DP;
    float v = (e < D_ && d < D_) ? W[e * D_ + d] : 0.f;
    Wb[i] = f2b(v);
}

// ---------------- K2: y (b,t,d f32) -> yT (b,d,t bf16), d padded to 304 ----
__global__ __launch_bounds__(256) void k_ytrans(const float* __restrict__ Y,
                                                unsigned short* __restrict__ yT){
    __shared__ float tile[64][65];
    const int bid = blockIdx.x;           // 64 * 16 * 5
    const int b  = bid / 80;
    const int tt = (bid % 80) / 5;
    const int dt = bid % 5;
    const int t0 = tt * 64, d0 = dt * 64;
    const int tid = threadIdx.x;
    const int dl = tid & 63, qq = tid >> 6;
    #pragma unroll
    for (int r = 0; r < 16; ++r){
        const int tl = qq * 16 + r;
        const int d = d0 + dl;
        float v = (d < D_) ? Y[((long)b * LY_ + t0 + tl) * D_ + d] : 0.f;
        tile[tl][dl] = v;
    }
    __syncthreads();
    #pragma unroll
    for (int r = 0; r < 16; ++r){
        const int drow = d0 + qq * 16 + r;
        if (drow < DV){
            float v = (drow < D_) ? tile[dl][qq * 16 + r] : 0.f;
            yT[((long)b * DV + drow) * LY_ + t0 + dl] = f2b(v);
        }
    }
}

// ---------------- K1: proj = relu(Z @ W^T + b), swapped-operand epilogue ----
__global__ __launch_bounds__(256) void k_proj(const float* __restrict__ X,
        const float* __restrict__ Y, const float* __restrict__ bias,
        const unsigned short* __restrict__ Wb,
        unsigned short* __restrict__ Px, unsigned short* __restrict__ Py){
    const int tid = threadIdx.x;
    const int w = tid >> 6, l = tid & 63;
    const int lr = l & 15, lg = l >> 4;
    const long m0 = (long)blockIdx.x * 128;
    const bool isX = (m0 < (long)B_ * LX_);
    const float* S = isX ? X : Y;
    unsigned short* Dst = isX ? Px : Py;
    const long base = isX ? m0 : m0 - (long)B_ * LX_;

    u32x4 a[2][10];
    #pragma unroll
    for (int ms = 0; ms < 2; ++ms){
        const float* rp = S + (base + 32 * w + 16 * ms + lr) * D_;
        #pragma unroll
        for (int ks = 0; ks < 10; ++ks){
            const int k0 = ks * 32 + lg * 8;
            f32x4 v0 = {0,0,0,0}, v1 = {0,0,0,0};
            if (k0 + 4 <= D_) v0 = *(const f32x4*)(rp + k0);
            if (k0 + 8 <= D_) v1 = *(const f32x4*)(rp + k0 + 4);
            u32x4 u;
            u[0] = pk_bf16(v0[0], v0[1]);
            u[1] = pk_bf16(v0[2], v0[3]);
            u[2] = pk_bf16(v1[0], v1[1]);
            u[3] = pk_bf16(v1[2], v1[3]);
            a[ms][ks] = u;
        }
    }

    #pragma unroll 2
    for (int es = 0; es < 20; ++es){
        f32x4 acc0 = {0,0,0,0}, acc1 = {0,0,0,0};
        const unsigned short* wp = Wb + (es * 16 + lr) * DP + lg * 8;
        #pragma unroll
        for (int ks = 0; ks < 10; ++ks){
            bf16x8 bf = ld_bf8(wp + ks * 32);       // A: row=e, k=d
            acc0 = mfma16(bf, __builtin_bit_cast(bf16x8, a[0][ks]), acc0);
            acc1 = mfma16(bf, __builtin_bit_cast(bf16x8, a[1][ks]), acc1);
        }
        // lane holds D[e = es*16 + 4*lg + r][m = lr]
        const int e0 = es * 16 + lg * 4;
        f32x4 bv = {0,0,0,0};
        if (e0 + 4 <= D_) bv = *(const f32x4*)(bias + e0);
        else {
            #pragma unroll
            for (int r = 0; r < 4; ++r) bv[r] = (e0 + r < D_) ? bias[e0 + r] : 0.f;
        }
        float s0[4], s1[4];
        #pragma unroll
        for (int r = 0; r < 4; ++r){
            float t0v = acc0[r] + bv[r]; s0[r] = t0v > 0.f ? t0v : 0.f;
            float t1v = acc1[r] + bv[r]; s1[r] = t1v > 0.f ? t1v : 0.f;
        }
        const u32x2 o0 = { pk_bf16(s0[0], s0[1]), pk_bf16(s0[2], s0[3]) };
        const u32x2 o1 = { pk_bf16(s1[0], s1[1]), pk_bf16(s1[2], s1[3]) };
        *(u32x2*)(Dst + (base + 32 * w + lr) * DP + e0)      = o0;
        *(u32x2*)(Dst + (base + 32 * w + 16 + lr) * DP + e0) = o1;
    }
}

// ---------------- K3: flash attention, 32 s-rows/wave (BM=128) --------------
// 1 wave/SIMD by design: LDS A/B fragments read ONCE per wave feed TWO
// 16-row s-groups -> per-output LDS traffic ~halves vs r4.
__global__ __launch_bounds__(256, 1) void k_attn(const int* __restrict__ mask,
        const unsigned short* __restrict__ Px, const unsigned short* __restrict__ Py,
        const unsigned short* __restrict__ yT, float* __restrict__ out){
    __shared__ unsigned short Yp_lds[KV][328];
    __shared__ unsigned short yT_lds[DV][40];
    __shared__ unsigned short P_lds[BM][40];     // [s within block][t]

    const int tid = threadIdx.x;
    const int w = tid >> 6, l = tid & 63;
    const int lr = l & 15, lg = l >> 4;

    // XCD swizzle: 8 s-blocks of a batch stay on one XCD
    const int bid = blockIdx.x;              // 512
    const int xcd = bid & 7;
    const int g = bid >> 3;                  // 0..63
    const int b = xcd + 8 * (g >> 3);
    const int s0 = (g & 7) * BM;

    // Q fragments: group 0 rows s0+16w+lr, group 1 rows s0+64+16w+lr
    u32x4 q0[10], q1[10];
    {
        const unsigned short* qp0 = Px + ((long)b * LX_ + s0 + 16 * w + lr) * DP + lg * 8;
        const unsigned short* qp1 = qp0 + 64 * DP;
        #pragma unroll
        for (int ks = 0; ks < 10; ++ks){ q0[ks] = *(const u32x4*)(qp0 + ks * 32);
                                         q1[ks] = *(const u32x4*)(qp1 + ks * 32); }
    }

    // staging addresses
    const unsigned short* srcYp[5];
    unsigned short*       dstYp[5];
    #pragma unroll
    for (int j = 0; j < 5; ++j){
        const int id = tid + 256 * j;            // 0..1279
        const int row = id / 40, c = id % 40;
        srcYp[j] = Py + ((long)b * LY_ + row) * DP + c * 8;
        dstYp[j] = &Yp_lds[row][c * 8];
    }
    const unsigned short* srcYT[5];
    unsigned short*       dstYT[5];
    #pragma unroll
    for (int j = 0; j < 5; ++j){
        const int id = tid + 256 * j;
        const int row = (id >> 2) < DV ? (id >> 2) : (DV - 1);
        const int c = id & 3;
        srcYT[j] = yT + ((long)b * DV + row) * LY_ + c * 8;
        dstYT[j] = &yT_lds[row][c * 8];
    }
    const bool v4 = (tid < 192);

    const int* mrow = mask + (long)b * LY_;

    // ---- prologue: stage tile 0 ----
    u32x4 pA[5], pT[5];
    #pragma unroll
    for (int j = 0; j < 5; ++j) pA[j] = *(const u32x4*)srcYp[j];
    #pragma unroll
    for (int j = 0; j < 4; ++j) pT[j] = *(const u32x4*)srcYT[j];
    if (v4) pT[4] = *(const u32x4*)srcYT[4];
    int4 m0v = *(const int4*)(mrow + lg * 4);
    int4 m1v = *(const int4*)(mrow + 16 + lg * 4);
    #pragma unroll
    for (int j = 0; j < 5; ++j) *(u32x4*)dstYp[j] = pA[j];
    #pragma unroll
    for (int j = 0; j < 4; ++j) *(u32x4*)dstYT[j] = pT[j];
    if (v4) *(u32x4*)dstYT[4] = pT[4];
    __syncthreads();

    f32x4 accA[19], accB[19];
    #pragma unroll
    for (int n = 0; n < 19; ++n){ accA[n] = f32x4{0,0,0,0}; accB[n] = f32x4{0,0,0,0}; }
    float mA = -INFINITY, lA = 0.f;   // group 0, s-row = s0+16w+lr
    float mB = -INFINITY, lB = 0.f;   // group 1, s-row = s0+64+16w+lr

    for (int it = 0; it < NT; ++it){
        const bool notlast = (it < NT - 1);

        // ---- A: issue next tile's global loads (skip if next fully masked) --
        int4 mn0, mn1;
        bool nextLoad = false;
        if (notlast){
            mn0 = *(const int4*)(mrow + (it + 1) * KV + lg * 4);
            mn1 = *(const int4*)(mrow + (it + 1) * KV + 16 + lg * 4);
            const int nall = (mn0.x && mn0.y && mn0.z && mn0.w &&
                              mn1.x && mn1.y && mn1.z && mn1.w) ? 1 : 0;
            nextLoad = !__all(nall);
            #pragma unroll
            for (int j = 0; j < 5; ++j) srcYp[j] += KV * DP;
            #pragma unroll
            for (int j = 0; j < 5; ++j) srcYT[j] += KV;
            if (nextLoad){
                #pragma unroll
                for (int j = 0; j < 5; ++j) pA[j] = *(const u32x4*)srcYp[j];
                #pragma unroll
                for (int j = 0; j < 4; ++j) pT[j] = *(const u32x4*)srcYT[j];
                if (v4) pT[4] = *(const u32x4*)srcYT[4];
            }
        }

        // ---- B: compute on current tile (skip if fully masked) ----
        const int allm = (m0v.x && m0v.y && m0v.z && m0v.w &&
                          m1v.x && m1v.y && m1v.z && m1v.w) ? 1 : 0;
        if (!__all(allm)){
            // S^T for both groups; A-fragments (Yp) read ONCE
            f32x4 sA0 = {0,0,0,0}, sA1 = {0,0,0,0}, sB0 = {0,0,0,0}, sB1 = {0,0,0,0};
            #pragma unroll
            for (int ks = 0; ks < 10; ++ks){
                bf16x8 a0 = ld_bf8(&Yp_lds[lr][ks * 32 + lg * 8]);
                bf16x8 a1 = ld_bf8(&Yp_lds[16 + lr][ks * 32 + lg * 8]);
                bf16x8 f0 = __builtin_bit_cast(bf16x8, q0[ks]);
                bf16x8 f1 = __builtin_bit_cast(bf16x8, q1[ks]);
                sA0 = mfma16(a0, f0, sA0);
                sA1 = mfma16(a1, f0, sA1);
                sB0 = mfma16(a0, f1, sB0);
                sB1 = mfma16(a1, f1, sB1);
            }

            const float ma0 = m0v.x ? -3.0e38f : 0.f, ma1 = m0v.y ? -3.0e38f : 0.f;
            const float ma2 = m0v.z ? -3.0e38f : 0.f, ma3 = m0v.w ? -3.0e38f : 0.f;
            const float mb0 = m1v.x ? -3.0e38f : 0.f, mb1 = m1v.y ? -3.0e38f : 0.f;
            const float mb2 = m1v.z ? -3.0e38f : 0.f, mb3 = m1v.w ? -3.0e38f : 0.f;

            // ---------- group A ----------
            {
                float v0[4] = { sA0[0]+ma0, sA0[1]+ma1, sA0[2]+ma2, sA0[3]+ma3 };
                float v1[4] = { sA1[0]+mb0, sA1[1]+mb1, sA1[2]+mb2, sA1[3]+mb3 };
                float mx = fmaxf(fmaxf(fmaxf(v0[0],v0[1]),fmaxf(v0[2],v0[3])),
                                 fmaxf(fmaxf(v1[0],v1[1]),fmaxf(v1[2],v1[3])));
                mx = fmaxf(mx, __shfl_xor(mx, 16));
                mx = fmaxf(mx, __shfl_xor(mx, 32));
                float p0[4], p1[4], ps = 0.f;
                if (__all(mx <= mA + 6.0f)){          // T13 defer-max: no rescale
                    #pragma unroll
                    for (int r = 0; r < 4; ++r){
                        p0[r] = __expf(v0[r] - mA); p1[r] = __expf(v1[r] - mA);
                        ps += p0[r] + p1[r];
                    }
                    ps += __shfl_xor(ps, 16); ps += __shfl_xor(ps, 32);
                    lA += ps;
                } else {
                    const float nm = fmaxf(mA, mx);
                    #pragma unroll
                    for (int r = 0; r < 4; ++r){
                        p0[r] = __expf(v0[r] - nm); p1[r] = __expf(v1[r] - nm);
                        ps += p0[r] + p1[r];
                    }
                    ps += __shfl_xor(ps, 16); ps += __shfl_xor(ps, 32);
                    const float sc = __expf(mA - nm);
                    lA = lA * sc + ps; mA = nm;
                    float scr[4];
                    #pragma unroll
                    for (int r = 0; r < 4; ++r) scr[r] = __shfl(sc, lg * 4 + r);
                    #pragma unroll
                    for (int n = 0; n < 19; ++n){
                        #pragma unroll
                        for (int r = 0; r < 4; ++r) accA[n][r] *= scr[r];
                    }
                }
                *(u32x2*)&P_lds[16 * w + lr][4 * lg]      = u32x2{ pk_bf16(p0[0],p0[1]), pk_bf16(p0[2],p0[3]) };
                *(u32x2*)&P_lds[16 * w + lr][16 + 4 * lg] = u32x2{ pk_bf16(p1[0],p1[1]), pk_bf16(p1[2],p1[3]) };
            }
            // ---------- group B ----------
            {
                float v0[4] = { sB0[0]+ma0, sB0[1]+ma1, sB0[2]+ma2, sB0[3]+ma3 };
                float v1[4] = { sB1[0]+mb0, sB1[1]+mb1, sB1[2]+mb2, sB1[3]+mb3 };
                float mx = fmaxf(fmaxf(fmaxf(v0[0],v0[1]),fmaxf(v0[2],v0[3])),
                                 fmaxf(fmaxf(v1[0],v1[1]),fmaxf(v1[2],v1[3])));
                mx = fmaxf(mx, __shfl_xor(mx, 16));
                mx = fmaxf(mx, __shfl_xor(mx, 32));
                float p0[4], p1[4], ps = 0.f;
                if (__all(mx <= mB + 6.0f)){
                    #pragma unroll
                    for (int r = 0; r < 4; ++r){
                        p0[r] = __expf(v0[r] - mB); p1[r] = __expf(v1[r] - mB);
                        ps += p0[r] + p1[r];
                    }
                    ps += __shfl_xor(ps, 16); ps += __shfl_xor(ps, 32);
                    lB += ps;
                } else {
                    const float nm = fmaxf(mB, mx);
                    #pragma unroll
                    for (int r = 0; r < 4; ++r){
                        p0[r] = __expf(v0[r] - nm); p1[r] = __expf(v1[r] - nm);
                        ps += p0[r] + p1[r];
                    }
                    ps += __shfl_xor(ps, 16); ps += __shfl_xor(ps, 32);
                    const float sc = __expf(mB - nm);
                    lB = lB * sc + ps; mB = nm;
                    float scr[4];
                    #pragma unroll
                    for (int r = 0; r < 4; ++r) scr[r] = __shfl(sc, lg * 4 + r);
                    #pragma unroll
                    for (int n = 0; n < 19; ++n){
                        #pragma unroll
                        for (int r = 0; r < 4; ++r) accB[n][r] *= scr[r];
                    }
                }
                *(u32x2*)&P_lds[64 + 16 * w + lr][4 * lg]      = u32x2{ pk_bf16(p0[0],p0[1]), pk_bf16(p0[2],p0[3]) };
                *(u32x2*)&P_lds[64 + 16 * w + lr][16 + 4 * lg] = u32x2{ pk_bf16(p1[0],p1[1]), pk_bf16(p1[2],p1[3]) };
            }

            // O += P @ y : vf read ONCE feeds both groups
            bf16x8 pf0 = ld_bf8(&P_lds[16 * w + lr][lg * 8]);
            bf16x8 pf1 = ld_bf8(&P_lds[64 + 16 * w + lr][lg * 8]);
            #pragma unroll
            for (int n = 0; n < 19; ++n){
                bf16x8 vf = ld_bf8(&yT_lds[n * 16 + lr][lg * 8]);
                accA[n] = mfma16(pf0, vf, accA[n]);
                accB[n] = mfma16(pf1, vf, accB[n]);
            }
        }

        __syncthreads();           // all waves done reading LDS
        if (notlast){
            if (nextLoad){
                #pragma unroll
                for (int j = 0; j < 5; ++j) *(u32x4*)dstYp[j] = pA[j];
                #pragma unroll
                for (int j = 0; j < 4; ++j) *(u32x4*)dstYT[j] = pT[j];
                if (v4) *(u32x4*)dstYT[4] = pT[4];
            }
            m0v = mn0; m1v = mn1;
        }
        __syncthreads();           // LDS ready for next iteration
    }

    // normalize + store, both groups
    {
        const float il = 1.f / lA;
        float invr[4];
        #pragma unroll
        for (int r = 0; r < 4; ++r) invr[r] = __shfl(il, lg * 4 + r);
        #pragma unroll
        for (int n = 0; n < 19; ++n){
            const int d = n * 16 + lr;
            if (d < D_){
                #pragma unroll
                for (int r = 0; r < 4; ++r)
                    out[((long)b * LX_ + s0 + 16 * w + lg * 4 + r) * D_ + d] = accA[n][r] * invr[r];
            }
        }
    }
    {
        const float il = 1.f / lB;
        float invr[4];
        #pragma unroll
        for (int r = 0; r < 4; ++r) invr[r] = __shfl(il, lg * 4 + r);
        #pragma unroll
        for (int n = 0; n < 19; ++n){
            const int d = n * 16 + lr;
            if (d < D_){
                #pragma unroll
                for (int r = 0; r < 4; ++r)
                    out[((long)b * LX_ + s0 + 64 + 16 * w + lg * 4 + r) * D_ + d] = accB[n][r] * invr[r];
            }
        }
    }
}

extern "C" void kernel_launch(void* const* d_in, const int* in_sizes, int n_in,
                              void* d_out, int out_size, void* d_ws, size_t ws_size,
                              hipStream_t stream){
    const float* x = (const float*)d_in[0];
    const float* y = (const float*)d_in[1];
    const int* ymask = (const int*)d_in[2];
    const float* W = (const float*)d_in[3];
    const float* bias = (const float*)d_in[4];
    float* out = (float*)d_out;

    unsigned short* Wb  = (unsigned short*)d_ws;
    unsigned short* Px  = (unsigned short*)((char*)d_ws + (1 << 18));
    unsigned short* Py  = (unsigned short*)((char*)d_ws + (1 << 18) + 41943040LL);
    unsigned short* yTw = (unsigned short*)((char*)d_ws + (1 << 18) + 83886080LL);

    hipLaunchKernelGGL(k_wconv, dim3((DP * DP + 255) / 256), dim3(256), 0, stream, W, Wb);
    hipLaunchKernelGGL(k_proj,  dim3(1024), dim3(256), 0, stream, x, y, bias, Wb, Px, Py);
    hipLaunchKernelGGL(k_ytrans, dim3(64 * 80), dim3(256), 0, stream, y, yTw);
    hipLaunchKernelGGL(k_attn,  dim3(512), dim3(256), 0, stream, ymask, Px, Py, yTw, out);
}

// Round 8
// 535.607 us; speedup vs baseline: 1.1892x; 1.1154x over previous
//
#include <hip/hip_runtime.h>
#include <cmath>

#define B_   64
#define LX_  1024
#define LY_  1024
#define D_   300
#define DP   320      // padded K / e dimension
#define DV   304      // padded d for PV (19 * 16)
#define BM   64       // s-tile rows per block (flash attn)
#define KV   32       // t-tile
#define NT   (LY_ / KV)

using f32x4  = __attribute__((ext_vector_type(4))) float;
using bf16x8 = __attribute__((ext_vector_type(8))) __bf16;
using u32x4  = __attribute__((ext_vector_type(4))) unsigned int;
using u32x2  = __attribute__((ext_vector_type(2))) unsigned int;

static __device__ __forceinline__ unsigned short f2b(float f){
    unsigned u = __builtin_bit_cast(unsigned, f);
    u += 0x7FFFu + ((u >> 16) & 1u);          // round-to-nearest-even
    return (unsigned short)(u >> 16);
}

static __device__ __forceinline__ unsigned pk_bf16(float lo, float hi){
    unsigned r;
    asm volatile("v_cvt_pk_bf16_f32 %0, %1, %2" : "=v"(r) : "v"(lo), "v"(hi));
    return r;
}

static __device__ __forceinline__ bf16x8 ld_bf8(const unsigned short* p){
    u32x4 u = *(const u32x4*)p;
    return __builtin_bit_cast(bf16x8, u);
}

static __device__ __forceinline__ f32x4 mfma16(bf16x8 a, bf16x8 b, f32x4 c){
    return __builtin_amdgcn_mfma_f32_16x16x32_bf16(a, b, c, 0, 0, 0);
}

// ---------------- K0: W (300x300 f32) -> Wb (320x320 bf16, zero padded) ----
__global__ void k_wconv(const float* __restrict__ W, unsigned short* __restrict__ Wb){
    int i = blockIdx.x * 256 + threadIdx.x;
    if (i >= DP * DP) return;
    int e = i / DP, d = i % DP;
    float v = (e < D_ && d < D_) ? W[e * D_ + d] : 0.f;
    Wb[i] = f2b(v);
}

// ---------------- K2: y (b,t,d f32) -> yT (b,d,t bf16), d padded to 304 ----
__global__ __launch_bounds__(256) void k_ytrans(const float* __restrict__ Y,
                                                unsigned short* __restrict__ yT){
    __shared__ float tile[64][65];
    const int bid = blockIdx.x;           // 64 * 16 * 5
    const int b  = bid / 80;
    const int tt = (bid % 80) / 5;
    const int dt = bid % 5;
    const int t0 = tt * 64, d0 = dt * 64;
    const int tid = threadIdx.x;
    const int dl = tid & 63, qq = tid >> 6;
    #pragma unroll
    for (int r = 0; r < 16; ++r){
        const int tl = qq * 16 + r;
        const int d = d0 + dl;
        float v = (d < D_) ? Y[((long)b * LY_ + t0 + tl) * D_ + d] : 0.f;
        tile[tl][dl] = v;
    }
    __syncthreads();
    #pragma unroll
    for (int r = 0; r < 16; ++r){
        const int drow = d0 + qq * 16 + r;
        if (drow < DV){
            float v = (drow < D_) ? tile[dl][qq * 16 + r] : 0.f;
            yT[((long)b * DV + drow) * LY_ + t0 + dl] = f2b(v);
        }
    }
}

// ---------------- K1: proj = relu(Z @ W^T + b), swapped-operand epilogue ----
__global__ __launch_bounds__(256) void k_proj(const float* __restrict__ X,
        const float* __restrict__ Y, const float* __restrict__ bias,
        const unsigned short* __restrict__ Wb,
        unsigned short* __restrict__ Px, unsigned short* __restrict__ Py){
    const int tid = threadIdx.x;
    const int w = tid >> 6, l = tid & 63;
    const int lr = l & 15, lg = l >> 4;
    const long m0 = (long)blockIdx.x * 128;
    const bool isX = (m0 < (long)B_ * LX_);
    const float* S = isX ? X : Y;
    unsigned short* Dst = isX ? Px : Py;
    const long base = isX ? m0 : m0 - (long)B_ * LX_;

    u32x4 a[2][10];
    #pragma unroll
    for (int ms = 0; ms < 2; ++ms){
        const float* rp = S + (base + 32 * w + 16 * ms + lr) * D_;
        #pragma unroll
        for (int ks = 0; ks < 10; ++ks){
            const int k0 = ks * 32 + lg * 8;
            f32x4 v0 = {0,0,0,0}, v1 = {0,0,0,0};
            if (k0 + 4 <= D_) v0 = *(const f32x4*)(rp + k0);
            if (k0 + 8 <= D_) v1 = *(const f32x4*)(rp + k0 + 4);
            u32x4 u;
            u[0] = pk_bf16(v0[0], v0[1]);
            u[1] = pk_bf16(v0[2], v0[3]);
            u[2] = pk_bf16(v1[0], v1[1]);
            u[3] = pk_bf16(v1[2], v1[3]);
            a[ms][ks] = u;
        }
    }

    #pragma unroll 2
    for (int es = 0; es < 20; ++es){
        f32x4 acc0 = {0,0,0,0}, acc1 = {0,0,0,0};
        const unsigned short* wp = Wb + (es * 16 + lr) * DP + lg * 8;
        #pragma unroll
        for (int ks = 0; ks < 10; ++ks){
            bf16x8 bf = ld_bf8(wp + ks * 32);       // A: row=e, k=d
            acc0 = mfma16(bf, __builtin_bit_cast(bf16x8, a[0][ks]), acc0);
            acc1 = mfma16(bf, __builtin_bit_cast(bf16x8, a[1][ks]), acc1);
        }
        // lane holds D[e = es*16 + 4*lg + r][m = lr]
        const int e0 = es * 16 + lg * 4;
        f32x4 bv = {0,0,0,0};
        if (e0 + 4 <= D_) bv = *(const f32x4*)(bias + e0);
        else {
            #pragma unroll
            for (int r = 0; r < 4; ++r) bv[r] = (e0 + r < D_) ? bias[e0 + r] : 0.f;
        }
        float s0[4], s1[4];
        #pragma unroll
        for (int r = 0; r < 4; ++r){
            float t0v = acc0[r] + bv[r]; s0[r] = t0v > 0.f ? t0v : 0.f;
            float t1v = acc1[r] + bv[r]; s1[r] = t1v > 0.f ? t1v : 0.f;
        }
        const u32x2 o0 = { pk_bf16(s0[0], s0[1]), pk_bf16(s0[2], s0[3]) };
        const u32x2 o1 = { pk_bf16(s1[0], s1[1]), pk_bf16(s1[2], s1[3]) };
        *(u32x2*)(Dst + (base + 32 * w + lr) * DP + e0)      = o0;
        *(u32x2*)(Dst + (base + 32 * w + 16 + lr) * DP + e0) = o1;
    }
}

// ---------------- K3: flash attention (r4 structure + defer-max + skip-stage)
// mask is int32: 0 = keep, nonzero = masked out
__global__ __launch_bounds__(256, 2) void k_attn(const int* __restrict__ mask,
        const unsigned short* __restrict__ Px, const unsigned short* __restrict__ Py,
        const unsigned short* __restrict__ yT, float* __restrict__ out){
    __shared__ unsigned short Yp_lds[KV][328];   // odd chunk-stride: conflict-light b128
    __shared__ unsigned short yT_lds[DV][40];
    __shared__ unsigned short P_lds[BM][40];     // [s within block][t]

    const int tid = threadIdx.x;
    const int w = tid >> 6, l = tid & 63;
    const int lr = l & 15, lg = l >> 4;

    // XCD-bijective swizzle: all 16 s-blocks of a batch land on one XCD
    const int bid = blockIdx.x;              // 1024
    const int xcd = bid & 7;
    const int g = bid >> 3;
    const int b = xcd + 8 * (g >> 4);
    const int s0 = (g & 15) * BM;

    // Q fragments: wave w owns rows s0+16w .. s0+16w+15 (B-operand: col = lr)
    u32x4 q[10];
    {
        const unsigned short* qp = Px + ((long)b * LX_ + s0 + 16 * w + lr) * DP + lg * 8;
        #pragma unroll
        for (int ks = 0; ks < 10; ++ks) q[ks] = *(const u32x4*)(qp + ks * 32);
    }

    // ---- staging address setup (per thread, loop-invariant row/col) ----
    const unsigned short* srcYp[5];
    unsigned short*       dstYp[5];
    #pragma unroll
    for (int j = 0; j < 5; ++j){
        const int id = tid + 256 * j;            // 0..1279
        const int row = id / 40, c = id % 40;
        srcYp[j] = Py + ((long)b * LY_ + row) * DP + c * 8;
        dstYp[j] = &Yp_lds[row][c * 8];
    }
    const unsigned short* srcYT[5];
    unsigned short*       dstYT[5];
    #pragma unroll
    for (int j = 0; j < 5; ++j){
        const int id = tid + 256 * j;            // valid if < 1216
        const int row = (id >> 2) < DV ? (id >> 2) : (DV - 1);
        const int c = id & 3;
        srcYT[j] = yT + ((long)b * DV + row) * LY_ + c * 8;
        dstYT[j] = &yT_lds[row][c * 8];
    }
    const bool v4 = (tid < 192);                 // j=4 validity for yT chunks

    const int* mrow = mask + (long)b * LY_;

    // ---- prologue: stage tile 0 ----
    u32x4 pA[5], pT[5];
    #pragma unroll
    for (int j = 0; j < 5; ++j) pA[j] = *(const u32x4*)srcYp[j];
    #pragma unroll
    for (int j = 0; j < 4; ++j) pT[j] = *(const u32x4*)srcYT[j];
    if (v4) pT[4] = *(const u32x4*)srcYT[4];
    int4 m0v = *(const int4*)(mrow + lg * 4);
    int4 m1v = *(const int4*)(mrow + 16 + lg * 4);
    #pragma unroll
    for (int j = 0; j < 5; ++j) *(u32x4*)dstYp[j] = pA[j];
    #pragma unroll
    for (int j = 0; j < 4; ++j) *(u32x4*)dstYT[j] = pT[j];
    if (v4) *(u32x4*)dstYT[4] = pT[4];
    __syncthreads();

    f32x4 acc[19];
    #pragma unroll
    for (int n = 0; n < 19; ++n) acc[n] = f32x4{0,0,0,0};
    float m_r = -INFINITY;    // running max for s-row = s0+16w+lr
    float l_r = 0.f;

    for (int it = 0; it < NT; ++it){
        const bool notlast = (it < NT - 1);

        // ---- A: issue next tile's global loads (skip if next fully masked) --
        int4 mn0, mn1;
        bool nextLoad = false;
        if (notlast){
            mn0 = *(const int4*)(mrow + (it + 1) * KV + lg * 4);
            mn1 = *(const int4*)(mrow + (it + 1) * KV + 16 + lg * 4);
            const int nall = (mn0.x && mn0.y && mn0.z && mn0.w &&
                              mn1.x && mn1.y && mn1.z && mn1.w) ? 1 : 0;
            nextLoad = !__all(nall);
            #pragma unroll
            for (int j = 0; j < 5; ++j) srcYp[j] += KV * DP;
            #pragma unroll
            for (int j = 0; j < 5; ++j) srcYT[j] += KV;
            if (nextLoad){
                #pragma unroll
                for (int j = 0; j < 5; ++j) pA[j] = *(const u32x4*)srcYp[j];
                #pragma unroll
                for (int j = 0; j < 4; ++j) pT[j] = *(const u32x4*)srcYT[j];
                if (v4) pT[4] = *(const u32x4*)srcYT[4];
            }
        }

        // ---- B: compute on current tile (skip if fully masked) ----
        const int allm = (m0v.x && m0v.y && m0v.z && m0v.w &&
                          m1v.x && m1v.y && m1v.z && m1v.w) ? 1 : 0;
        if (!__all(allm)){
            // S^T = Yp @ Q^T : lane holds S[t = it*KV + 16*sub + 4*lg + r][s = s0+16w+lr]
            f32x4 sv0 = {0,0,0,0}, sv1 = {0,0,0,0};
            #pragma unroll
            for (int ks = 0; ks < 10; ++ks){
                bf16x8 qf = __builtin_bit_cast(bf16x8, q[ks]);
                bf16x8 a0 = ld_bf8(&Yp_lds[lr][ks * 32 + lg * 8]);
                bf16x8 a1 = ld_bf8(&Yp_lds[16 + lr][ks * 32 + lg * 8]);
                sv0 = mfma16(a0, qf, sv0);
                sv1 = mfma16(a1, qf, sv1);
            }

            float v0[4], v1[4];
            v0[0] = sv0[0] + (m0v.x ? -3.0e38f : 0.f);
            v0[1] = sv0[1] + (m0v.y ? -3.0e38f : 0.f);
            v0[2] = sv0[2] + (m0v.z ? -3.0e38f : 0.f);
            v0[3] = sv0[3] + (m0v.w ? -3.0e38f : 0.f);
            v1[0] = sv1[0] + (m1v.x ? -3.0e38f : 0.f);
            v1[1] = sv1[1] + (m1v.y ? -3.0e38f : 0.f);
            v1[2] = sv1[2] + (m1v.z ? -3.0e38f : 0.f);
            v1[3] = sv1[3] + (m1v.w ? -3.0e38f : 0.f);

            float mx = fmaxf(fmaxf(fmaxf(v0[0], v0[1]), fmaxf(v0[2], v0[3])),
                             fmaxf(fmaxf(v1[0], v1[1]), fmaxf(v1[2], v1[3])));
            mx = fmaxf(mx, __shfl_xor(mx, 16));
            mx = fmaxf(mx, __shfl_xor(mx, 32));

            float p0[4], p1[4], ps = 0.f;
            if (__all(mx <= m_r + 6.0f)){          // T13 defer-max: no rescale pass
                #pragma unroll
                for (int r = 0; r < 4; ++r){
                    p0[r] = __expf(v0[r] - m_r);
                    p1[r] = __expf(v1[r] - m_r);
                    ps += p0[r] + p1[r];
                }
                ps += __shfl_xor(ps, 16);
                ps += __shfl_xor(ps, 32);
                l_r += ps;
            } else {
                const float nm = fmaxf(m_r, mx);
                #pragma unroll
                for (int r = 0; r < 4; ++r){
                    p0[r] = __expf(v0[r] - nm);
                    p1[r] = __expf(v1[r] - nm);
                    ps += p0[r] + p1[r];
                }
                ps += __shfl_xor(ps, 16);
                ps += __shfl_xor(ps, 32);
                const float sc = __expf(m_r - nm);   // first tile: exp(-inf)=0
                l_r = l_r * sc + ps;
                m_r = nm;
                float scr[4];
                #pragma unroll
                for (int r = 0; r < 4; ++r) scr[r] = __shfl(sc, lg * 4 + r);
                #pragma unroll
                for (int n = 0; n < 19; ++n){
                    #pragma unroll
                    for (int r = 0; r < 4; ++r) acc[n][r] *= scr[r];
                }
            }

            // pack P -> bf16, write own wave's rows (within-wave dependency only)
            const unsigned c00 = pk_bf16(p0[0], p0[1]);
            const unsigned c01 = pk_bf16(p0[2], p0[3]);
            const unsigned c10 = pk_bf16(p1[0], p1[1]);
            const unsigned c11 = pk_bf16(p1[2], p1[3]);
            *(u32x2*)&P_lds[16 * w + lr][4 * lg]      = u32x2{c00, c01};
            *(u32x2*)&P_lds[16 * w + lr][16 + 4 * lg] = u32x2{c10, c11};

            // O += P @ y
            bf16x8 pf = ld_bf8(&P_lds[16 * w + lr][lg * 8]);
            #pragma unroll
            for (int n = 0; n < 19; ++n){
                bf16x8 vf = ld_bf8(&yT_lds[n * 16 + lr][lg * 8]);
                acc[n] = mfma16(pf, vf, acc[n]);
            }
        }

        __syncthreads();           // all waves done reading LDS
        if (notlast){
            if (nextLoad){
                #pragma unroll
                for (int j = 0; j < 5; ++j) *(u32x4*)dstYp[j] = pA[j];
                #pragma unroll
                for (int j = 0; j < 4; ++j) *(u32x4*)dstYT[j] = pT[j];
                if (v4) *(u32x4*)dstYT[4] = pT[4];
            }
            m0v = mn0; m1v = mn1;
        }
        __syncthreads();           // LDS ready for next iteration
    }

    // normalize: 1/l for rows s = 4*lg + r via broadcast
    const float il = 1.f / l_r;
    float invr[4];
    #pragma unroll
    for (int r = 0; r < 4; ++r) invr[r] = __shfl(il, lg * 4 + r);

    #pragma unroll
    for (int n = 0; n < 19; ++n){
        const int d = n * 16 + lr;
        if (d < D_){
            #pragma unroll
            for (int r = 0; r < 4; ++r){
                out[((long)b * LX_ + s0 + 16 * w + lg * 4 + r) * D_ + d] = acc[n][r] * invr[r];
            }
        }
    }
}

extern "C" void kernel_launch(void* const* d_in, const int* in_sizes, int n_in,
                              void* d_out, int out_size, void* d_ws, size_t ws_size,
                              hipStream_t stream){
    const float* x = (const float*)d_in[0];
    const float* y = (const float*)d_in[1];
    const int* ymask = (const int*)d_in[2];
    const float* W = (const float*)d_in[3];
    const float* bias = (const float*)d_in[4];
    float* out = (float*)d_out;

    unsigned short* Wb  = (unsigned short*)d_ws;
    unsigned short* Px  = (unsigned short*)((char*)d_ws + (1 << 18));
    unsigned short* Py  = (unsigned short*)((char*)d_ws + (1 << 18) + 41943040LL);
    unsigned short* yTw = (unsigned short*)((char*)d_ws + (1 << 18) + 83886080LL);

    hipLaunchKernelGGL(k_wconv, dim3((DP * DP + 255) / 256), dim3(256), 0, stream, W, Wb);
    hipLaunchKernelGGL(k_proj,  dim3(1024), dim3(256), 0, stream, x, y, bias, Wb, Px, Py);
    hipLaunchKernelGGL(k_ytrans, dim3(64 * 80), dim3(256), 0, stream, y, yTw);
    hipLaunchKernelGGL(k_attn,  dim3(1024), dim3(256), 0, stream, ymask, Px, Py, yTw, out);
}

// Round 9
// 352.494 us; speedup vs baseline: 1.8069x; 1.5195x over previous
//
#include <hip/hip_runtime.h>
#include <cmath>

#define B_   64
#define LX_  1024
#define LY_  1024
#define D_   300
#define DP   320      // padded K / e dimension
#define DV   304      // padded d for PV (19 * 16)
#define BM   64       // s-tile rows per block (flash attn)
#define KV   32       // t-tile
#define NT   (LY_ / KV)

using f32x4  = __attribute__((ext_vector_type(4))) float;
using bf16x8 = __attribute__((ext_vector_type(8))) __bf16;
using u32x4  = __attribute__((ext_vector_type(4))) unsigned int;
using u32x2  = __attribute__((ext_vector_type(2))) unsigned int;

static __device__ __forceinline__ unsigned short f2b(float f){
    unsigned u = __builtin_bit_cast(unsigned, f);
    u += 0x7FFFu + ((u >> 16) & 1u);          // round-to-nearest-even
    return (unsigned short)(u >> 16);
}

static __device__ __forceinline__ unsigned pk_bf16(float lo, float hi){
    unsigned r;
    asm volatile("v_cvt_pk_bf16_f32 %0, %1, %2" : "=v"(r) : "v"(lo), "v"(hi));
    return r;
}

static __device__ __forceinline__ bf16x8 ld_bf8(const unsigned short* p){
    u32x4 u = *(const u32x4*)p;
    return __builtin_bit_cast(bf16x8, u);
}

static __device__ __forceinline__ f32x4 mfma16(bf16x8 a, bf16x8 b, f32x4 c){
    return __builtin_amdgcn_mfma_f32_16x16x32_bf16(a, b, c, 0, 0, 0);
}

// async global->LDS DMA, 16B per lane; LDS dest = wave-uniform base + lane*16
static __device__ __forceinline__ void gload16(const unsigned short* g, unsigned short* l){
    __builtin_amdgcn_global_load_lds(
        (const __attribute__((address_space(1))) void*)g,
        (__attribute__((address_space(3))) void*)l, 16, 0, 0);
}

// ---------------- K0: W (300x300 f32) -> Wb (320x320 bf16, zero padded) ----
__global__ void k_wconv(const float* __restrict__ W, unsigned short* __restrict__ Wb){
    int i = blockIdx.x * 256 + threadIdx.x;
    if (i >= DP * DP) return;
    int e = i / DP, d = i % DP;
    float v = (e < D_ && d < D_) ? W[e * D_ + d] : 0.f;
    Wb[i] = f2b(v);
}

// ---------------- K2: y (b,t,d f32) -> yT (b,d,t bf16), d padded to 304 ----
__global__ __launch_bounds__(256) void k_ytrans(const float* __restrict__ Y,
                                                unsigned short* __restrict__ yT){
    __shared__ float tile[64][65];
    const int bid = blockIdx.x;           // 64 * 16 * 5
    const int b  = bid / 80;
    const int tt = (bid % 80) / 5;
    const int dt = bid % 5;
    const int t0 = tt * 64, d0 = dt * 64;
    const int tid = threadIdx.x;
    const int dl = tid & 63, qq = tid >> 6;
    #pragma unroll
    for (int r = 0; r < 16; ++r){
        const int tl = qq * 16 + r;
        const int d = d0 + dl;
        float v = (d < D_) ? Y[((long)b * LY_ + t0 + tl) * D_ + d] : 0.f;
        tile[tl][dl] = v;
    }
    __syncthreads();
    #pragma unroll
    for (int r = 0; r < 16; ++r){
        const int drow = d0 + qq * 16 + r;
        if (drow < DV){
            float v = (drow < D_) ? tile[dl][qq * 16 + r] : 0.f;
            yT[((long)b * DV + drow) * LY_ + t0 + dl] = f2b(v);
        }
    }
}

// ---------------- K1: proj = relu(Z @ W^T + b), swapped-operand epilogue ----
__global__ __launch_bounds__(256) void k_proj(const float* __restrict__ X,
        const float* __restrict__ Y, const float* __restrict__ bias,
        const unsigned short* __restrict__ Wb,
        unsigned short* __restrict__ Px, unsigned short* __restrict__ Py){
    const int tid = threadIdx.x;
    const int w = tid >> 6, l = tid & 63;
    const int lr = l & 15, lg = l >> 4;
    const long m0 = (long)blockIdx.x * 128;
    const bool isX = (m0 < (long)B_ * LX_);
    const float* S = isX ? X : Y;
    unsigned short* Dst = isX ? Px : Py;
    const long base = isX ? m0 : m0 - (long)B_ * LX_;

    u32x4 a[2][10];
    #pragma unroll
    for (int ms = 0; ms < 2; ++ms){
        const float* rp = S + (base + 32 * w + 16 * ms + lr) * D_;
        #pragma unroll
        for (int ks = 0; ks < 10; ++ks){
            const int k0 = ks * 32 + lg * 8;
            f32x4 v0 = {0,0,0,0}, v1 = {0,0,0,0};
            if (k0 + 4 <= D_) v0 = *(const f32x4*)(rp + k0);
            if (k0 + 8 <= D_) v1 = *(const f32x4*)(rp + k0 + 4);
            u32x4 u;
            u[0] = pk_bf16(v0[0], v0[1]);
            u[1] = pk_bf16(v0[2], v0[3]);
            u[2] = pk_bf16(v1[0], v1[1]);
            u[3] = pk_bf16(v1[2], v1[3]);
            a[ms][ks] = u;
        }
    }

    #pragma unroll 2
    for (int es = 0; es < 20; ++es){
        f32x4 acc0 = {0,0,0,0}, acc1 = {0,0,0,0};
        const unsigned short* wp = Wb + (es * 16 + lr) * DP + lg * 8;
        #pragma unroll
        for (int ks = 0; ks < 10; ++ks){
            bf16x8 bf = ld_bf8(wp + ks * 32);       // A: row=e, k=d
            acc0 = mfma16(bf, __builtin_bit_cast(bf16x8, a[0][ks]), acc0);
            acc1 = mfma16(bf, __builtin_bit_cast(bf16x8, a[1][ks]), acc1);
        }
        // lane holds D[e = es*16 + 4*lg + r][m = lr]
        const int e0 = es * 16 + lg * 4;
        f32x4 bv = {0,0,0,0};
        if (e0 + 4 <= D_) bv = *(const f32x4*)(bias + e0);
        else {
            #pragma unroll
            for (int r = 0; r < 4; ++r) bv[r] = (e0 + r < D_) ? bias[e0 + r] : 0.f;
        }
        float s0[4], s1[4];
        #pragma unroll
        for (int r = 0; r < 4; ++r){
            float t0v = acc0[r] + bv[r]; s0[r] = t0v > 0.f ? t0v : 0.f;
            float t1v = acc1[r] + bv[r]; s1[r] = t1v > 0.f ? t1v : 0.f;
        }
        const u32x2 o0 = { pk_bf16(s0[0], s0[1]), pk_bf16(s0[2], s0[3]) };
        const u32x2 o1 = { pk_bf16(s1[0], s1[1]), pk_bf16(s1[2], s1[3]) };
        *(u32x2*)(Dst + (base + 32 * w + lr) * DP + e0)      = o0;
        *(u32x2*)(Dst + (base + 32 * w + 16 + lr) * DP + e0) = o1;
    }
}

// ---------------- K3: flash attention (global_load_lds + XOR swizzle) -------
// LDS linear (DMA-written); conflict-avoidance via the SAME involution applied
// to the global SOURCE chunk and the LDS READ chunk (guide rule #21).
__global__ __launch_bounds__(256, 2) void k_attn(const int* __restrict__ mask,
        const unsigned short* __restrict__ Px, const unsigned short* __restrict__ Py,
        const unsigned short* __restrict__ yT, float* __restrict__ out){
    __shared__ unsigned short Yp_lds[KV][320];   // linear, 40 chunks/row
    __shared__ unsigned short yT_lds[DV][32];    // linear, 4 chunks/row
    __shared__ unsigned short P_lds[BM][40];     // padded (ds-written)

    const int tid = threadIdx.x;
    const int w = tid >> 6, l = tid & 63;
    const int lr = l & 15, lg = l >> 4;
    const int sw3 = lr & 7;          // Yp read swizzle: chunk ^= sw3
    const int s2  = (lr >> 1) & 3;   // yT read swizzle: chunk ^= s2

    // XCD-bijective swizzle: all 16 s-blocks of a batch land on one XCD
    const int bid = blockIdx.x;              // 1024
    const int xcd = bid & 7;
    const int g = bid >> 3;
    const int b = xcd + 8 * (g >> 4);
    const int s0 = (g & 15) * BM;

    // Q fragments: wave w owns rows s0+16w .. s0+16w+15 (B-operand: col = lr)
    u32x4 q[10];
    {
        const unsigned short* qp = Px + ((long)b * LX_ + s0 + 16 * w + lr) * DP + lg * 8;
        #pragma unroll
        for (int ks = 0; ks < 10; ++ks) q[ks] = *(const u32x4*)(qp + ks * 32);
    }

    // per-lane PRE-SWIZZLED global source pointers (advance per t-iter)
    const unsigned short* srcYp[5];
    #pragma unroll
    for (int j = 0; j < 5; ++j){
        const int id = tid + 256 * j;            // 0..1279
        const int row = id / 40, c = id % 40;
        srcYp[j] = Py + ((long)b * LY_ + row) * DP + (c ^ (row & 7)) * 8;
    }
    const unsigned short* srcYT[5];
    #pragma unroll
    for (int j = 0; j < 5; ++j){
        int id = tid + 256 * j; if (id > 1215) id = 1215;   // w3/j4 lanes unused
        const int row = id >> 2, c = id & 3;
        srcYT[j] = yT + ((long)b * DV + row) * LY_ + (c ^ ((row >> 1) & 3)) * 8;
    }
    // wave-uniform LDS DMA bases (chunk 64*w + 256*j -> u16 offset *8)
    unsigned short* const ldsYp_w = &Yp_lds[0][0] + w * 512;
    unsigned short* const ldsYT_w = &yT_lds[0][0] + w * 512;

    const int* mrow = mask + (long)b * LY_;

    // ---- prologue: stage tile 0 via DMA ----
    #pragma unroll
    for (int j = 0; j < 5; ++j) gload16(srcYp[j], ldsYp_w + j * 2048);
    #pragma unroll
    for (int j = 0; j < 4; ++j) gload16(srcYT[j], ldsYT_w + j * 2048);
    if (w < 3) gload16(srcYT[4], ldsYT_w + 4 * 2048);
    int4 m0v = *(const int4*)(mrow + lg * 4);
    int4 m1v = *(const int4*)(mrow + 16 + lg * 4);
    asm volatile("s_waitcnt vmcnt(0)" ::: "memory");
    __syncthreads();

    f32x4 acc[19];
    #pragma unroll
    for (int n = 0; n < 19; ++n) acc[n] = f32x4{0,0,0,0};
    float m_r = -INFINITY;    // running max for s-row = s0+16w+lr
    float l_r = 0.f;

    for (int it = 0; it < NT; ++it){
        const bool notlast = (it < NT - 1);

        int4 mn0, mn1;
        bool nextLoad = false;
        if (notlast){
            mn0 = *(const int4*)(mrow + (it + 1) * KV + lg * 4);
            mn1 = *(const int4*)(mrow + (it + 1) * KV + 16 + lg * 4);
            const int nall = (mn0.x && mn0.y && mn0.z && mn0.w &&
                              mn1.x && mn1.y && mn1.z && mn1.w) ? 1 : 0;
            nextLoad = !__all(nall);
            #pragma unroll
            for (int j = 0; j < 5; ++j) srcYp[j] += KV * DP;
            #pragma unroll
            for (int j = 0; j < 5; ++j) srcYT[j] += KV;
        }

        // ---- compute on current tile (skip if fully masked) ----
        const int allm = (m0v.x && m0v.y && m0v.z && m0v.w &&
                          m1v.x && m1v.y && m1v.z && m1v.w) ? 1 : 0;
        if (!__all(allm)){
            // S^T = Yp @ Q^T : lane holds S[t = it*KV+16*sub+4*lg+r][s = s0+16w+lr]
            f32x4 sv0 = {0,0,0,0}, sv1 = {0,0,0,0};
            #pragma unroll
            for (int ks = 0; ks < 10; ++ks){
                const int cc = (((ks << 2) | lg) ^ sw3) << 3;    // swizzled u16 col
                bf16x8 qf = __builtin_bit_cast(bf16x8, q[ks]);
                bf16x8 a0 = ld_bf8(&Yp_lds[lr][cc]);
                bf16x8 a1 = ld_bf8(&Yp_lds[16 + lr][cc]);
                sv0 = mfma16(a0, qf, sv0);
                sv1 = mfma16(a1, qf, sv1);
            }

            float v0[4], v1[4];
            v0[0] = sv0[0] + (m0v.x ? -3.0e38f : 0.f);
            v0[1] = sv0[1] + (m0v.y ? -3.0e38f : 0.f);
            v0[2] = sv0[2] + (m0v.z ? -3.0e38f : 0.f);
            v0[3] = sv0[3] + (m0v.w ? -3.0e38f : 0.f);
            v1[0] = sv1[0] + (m1v.x ? -3.0e38f : 0.f);
            v1[1] = sv1[1] + (m1v.y ? -3.0e38f : 0.f);
            v1[2] = sv1[2] + (m1v.z ? -3.0e38f : 0.f);
            v1[3] = sv1[3] + (m1v.w ? -3.0e38f : 0.f);

            float mx = fmaxf(fmaxf(fmaxf(v0[0], v0[1]), fmaxf(v0[2], v0[3])),
                             fmaxf(fmaxf(v1[0], v1[1]), fmaxf(v1[2], v1[3])));
            mx = fmaxf(mx, __shfl_xor(mx, 16));
            mx = fmaxf(mx, __shfl_xor(mx, 32));

            float p0[4], p1[4], ps = 0.f;
            if (__all(mx <= m_r + 6.0f)){          // T13 defer-max: skip rescale
                #pragma unroll
                for (int r = 0; r < 4; ++r){
                    p0[r] = __expf(v0[r] - m_r);
                    p1[r] = __expf(v1[r] - m_r);
                    ps += p0[r] + p1[r];
                }
                ps += __shfl_xor(ps, 16);
                ps += __shfl_xor(ps, 32);
                l_r += ps;
            } else {
                const float nm = fmaxf(m_r, mx);
                #pragma unroll
                for (int r = 0; r < 4; ++r){
                    p0[r] = __expf(v0[r] - nm);
                    p1[r] = __expf(v1[r] - nm);
                    ps += p0[r] + p1[r];
                }
                ps += __shfl_xor(ps, 16);
                ps += __shfl_xor(ps, 32);
                const float sc = __expf(m_r - nm);   // first tile: exp(-inf)=0
                l_r = l_r * sc + ps;
                m_r = nm;
                float scr[4];
                #pragma unroll
                for (int r = 0; r < 4; ++r) scr[r] = __shfl(sc, lg * 4 + r);
                #pragma unroll
                for (int n = 0; n < 19; ++n){
                    #pragma unroll
                    for (int r = 0; r < 4; ++r) acc[n][r] *= scr[r];
                }
            }

            // pack P -> bf16, write own wave's rows (within-wave dependency only)
            const unsigned c00 = pk_bf16(p0[0], p0[1]);
            const unsigned c01 = pk_bf16(p0[2], p0[3]);
            const unsigned c10 = pk_bf16(p1[0], p1[1]);
            const unsigned c11 = pk_bf16(p1[2], p1[3]);
            *(u32x2*)&P_lds[16 * w + lr][4 * lg]      = u32x2{c00, c01};
            *(u32x2*)&P_lds[16 * w + lr][16 + 4 * lg] = u32x2{c10, c11};

            // O += P @ y (yT read with swizzled chunk)
            bf16x8 pf = ld_bf8(&P_lds[16 * w + lr][lg * 8]);
            const int vcc = (lg ^ s2) << 3;
            #pragma unroll
            for (int n = 0; n < 19; ++n){
                bf16x8 vf = ld_bf8(&yT_lds[n * 16 + lr][vcc]);
                acc[n] = mfma16(pf, vf, acc[n]);
            }
        }

        __syncthreads();           // all waves done reading LDS
        if (notlast && nextLoad){  // DMA next tile directly into LDS
            #pragma unroll
            for (int j = 0; j < 5; ++j) gload16(srcYp[j], ldsYp_w + j * 2048);
            #pragma unroll
            for (int j = 0; j < 4; ++j) gload16(srcYT[j], ldsYT_w + j * 2048);
            if (w < 3) gload16(srcYT[4], ldsYT_w + 4 * 2048);
        }
        if (notlast){ m0v = mn0; m1v = mn1; }
        asm volatile("s_waitcnt vmcnt(0)" ::: "memory");
        __syncthreads();           // LDS ready for next iteration
    }

    // normalize: 1/l for rows s = 4*lg + r via broadcast
    const float il = 1.f / l_r;
    float invr[4];
    #pragma unroll
    for (int r = 0; r < 4; ++r) invr[r] = __shfl(il, lg * 4 + r);

    #pragma unroll
    for (int n = 0; n < 19; ++n){
        const int d = n * 16 + lr;
        if (d < D_){
            #pragma unroll
            for (int r = 0; r < 4; ++r){
                out[((long)b * LX_ + s0 + 16 * w + lg * 4 + r) * D_ + d] = acc[n][r] * invr[r];
            }
        }
    }
}

extern "C" void kernel_launch(void* const* d_in, const int* in_sizes, int n_in,
                              void* d_out, int out_size, void* d_ws, size_t ws_size,
                              hipStream_t stream){
    const float* x = (const float*)d_in[0];
    const float* y = (const float*)d_in[1];
    const int* ymask = (const int*)d_in[2];
    const float* W = (const float*)d_in[3];
    const float* bias = (const float*)d_in[4];
    float* out = (float*)d_out;

    unsigned short* Wb  = (unsigned short*)d_ws;
    unsigned short* Px  = (unsigned short*)((char*)d_ws + (1 << 18));
    unsigned short* Py  = (unsigned short*)((char*)d_ws + (1 << 18) + 41943040LL);
    unsigned short* yTw = (unsigned short*)((char*)d_ws + (1 << 18) + 83886080LL);

    hipLaunchKernelGGL(k_wconv, dim3((DP * DP + 255) / 256), dim3(256), 0, stream, W, Wb);
    hipLaunchKernelGGL(k_proj,  dim3(1024), dim3(256), 0, stream, x, y, bias, Wb, Px, Py);
    hipLaunchKernelGGL(k_ytrans, dim3(64 * 80), dim3(256), 0, stream, y, yTw);
    hipLaunchKernelGGL(k_attn,  dim3(1024), dim3(256), 0, stream, ymask, Px, Py, yTw, out);
}